// Round 2
// baseline (2783.904 us; speedup 1.0000x reference)
//
#include <hip/hip_runtime.h>
#include <hip/hip_cooperative_groups.h>
#include <stdint.h>

typedef unsigned int uint;
typedef unsigned long long ull;
typedef __attribute__((ext_vector_type(8))) short short8;
typedef __attribute__((ext_vector_type(4))) float f32x4;
typedef __attribute__((ext_vector_type(4))) uint uintx4;

#define AS1 __attribute__((address_space(1)))
#define AS3 __attribute__((address_space(3)))

__device__ __forceinline__ unsigned short f2bf(float f) {
  uint u = __float_as_uint(f);
  u += 0x7fffu + ((u >> 16) & 1u);
  return (unsigned short)(u >> 16);
}
__device__ __forceinline__ float bfl(unsigned short s) {
  return __uint_as_float(((uint)s) << 16);
}

// ---------------- build kernels ----------------

// A[dir][m=t*8+b][e] = bf16(x or x_rev), 2 x 4096 x 1024
__global__ __launch_bounds__(256) void k_build_A(const float* __restrict__ x,
                                                 const int* __restrict__ lengths,
                                                 unsigned short* __restrict__ A) {
  int idx = blockIdx.x * 256 + threadIdx.x;   // float4 units, 2*1Mi total
  int dir = idx >> 20;
  int r = idx & 1048575;
  int m = r >> 8;
  int e4 = r & 255;
  int t = m >> 3, b = m & 7;
  int st = t;
  if (dir) { int len = lengths[b]; st = (t < len) ? (len - 1 - t) : t; }
  float4 v = *(const float4*)&x[((size_t)b * 512 + st) * 1024 + e4 * 4];
  ushort4 o;
  o.x = f2bf(v.x); o.y = f2bf(v.y); o.z = f2bf(v.z); o.w = f2bf(v.w);
  *(ushort4*)&A[(size_t)dir * 4194304 + (size_t)m * 1024 + e4 * 4] = o;
}

// Wp[dir][j][e] = bf16(W_ih)
__global__ __launch_bounds__(256) void k_cast_wih(const float* __restrict__ Wf,
                                                  const float* __restrict__ Wb,
                                                  unsigned short* __restrict__ Wp) {
  int idx = blockIdx.x * 256 + threadIdx.x;
  int dir = idx >> 20;
  int r = idx & 1048575;
  const float* src = dir ? Wb : Wf;
  float4 v = *(const float4*)&src[(size_t)r * 4];
  ushort4 o;
  o.x = f2bf(v.x); o.y = f2bf(v.y); o.z = f2bf(v.z); o.w = f2bf(v.w);
  *(ushort4*)&Wp[(size_t)dir * 4194304 + (size_t)r * 4] = o;
}

// WF (R11 layout): W_hh B-fragments, gate-regrouped so each wave's 16-wide n-tile
// holds ALL 4 gates for 4 hidden units.
// gtid = lane(6) | kt(5) | nt(1) | mc(7) | dir(1)
// n_local = lane&15: gate = n_local>>2, eri = n_local&3, er = nt*4+eri
// j = gate*1024 + mc*8 + er;  k = kt*32 + (lane>>4)*8 + v, v<8
__global__ __launch_bounds__(256) void k_build_wf(const float* __restrict__ Wf,
                                                  const float* __restrict__ Wb,
                                                  unsigned short* __restrict__ WF) {
  int gtid = blockIdx.x * 256 + threadIdx.x;   // 2^20
  int lane = gtid & 63;
  int kt   = (gtid >> 6) & 31;
  int nt   = (gtid >> 11) & 1;
  int mc   = (gtid >> 12) & 127;
  int dir  = (gtid >> 19) & 1;
  int gate = (lane & 15) >> 2;
  int eri  = lane & 3;
  int j = gate * 1024 + mc * 8 + nt * 4 + eri;
  int k0 = kt * 32 + (lane >> 4) * 8;
  const float* src = dir ? Wb : Wf;
  const float* s = &src[(size_t)j * 1024 + k0];
  float4 v0 = *(const float4*)s;
  float4 v1 = *(const float4*)(s + 4);
  ushort4 oa, ob;
  oa.x = f2bf(v0.x); oa.y = f2bf(v0.y); oa.z = f2bf(v0.z); oa.w = f2bf(v0.w);
  ob.x = f2bf(v1.x); ob.y = f2bf(v1.y); ob.z = f2bf(v1.z); ob.w = f2bf(v1.w);
  *(ushort4*)&WF[(size_t)gtid * 8] = oa;
  *(ushort4*)&WF[(size_t)gtid * 8 + 4] = ob;
}

// WET[e][k] = W_emit[k][e]  (fp32)
__global__ __launch_bounds__(256) void k_build_wet(const float* __restrict__ We,
                                                   float* __restrict__ WET) {
  int idx = blockIdx.x * 256 + threadIdx.x;  // 32768
  int e = idx >> 4, k = idx & 15;
  WET[(size_t)e * 16 + k] = We[(size_t)k * 2048 + e];
}

// ---------------- projection GEMM (bf16 MFMA): P[dir][m][j] = A @ W_ih^T + b ----------------
__global__ __launch_bounds__(256) void k_proj(const unsigned short* __restrict__ A,
                                              const unsigned short* __restrict__ Wp,
                                              const float* __restrict__ bfv,
                                              const float* __restrict__ bbv,
                                              unsigned short* __restrict__ P) {
  const int dir = blockIdx.z;
  const unsigned short* Ad = A + (size_t)dir * 4194304;
  const unsigned short* Wd = Wp + (size_t)dir * 4194304;
  const float* bias = dir ? bbv : bfv;
  unsigned short* Pd = P + (size_t)dir * 16777216;
  const int bm = blockIdx.x * 128;
  const int bn = blockIdx.y * 128;
  __shared__ unsigned short As[128 * 32];
  __shared__ unsigned short Bs[128 * 32];
  const int tid = threadIdx.x;
  const int w = tid >> 6, lane = tid & 63;
  const int wm = (w >> 1) * 64, wn = (w & 1) * 64;
  const int q = lane >> 4, rr = lane & 15;

  f32x4 acc[4][4];
#pragma unroll
  for (int i = 0; i < 4; ++i)
#pragma unroll
    for (int j = 0; j < 4; ++j) acc[i][j] = (f32x4){0.f, 0.f, 0.f, 0.f};

  for (int k0 = 0; k0 < 1024; k0 += 32) {
#pragma unroll
    for (int i = 0; i < 2; ++i) {
      int c = i * 256 + tid;
      int row = c >> 2, col = (c & 3) * 8;
      const unsigned short* ga = Ad + (size_t)(bm + row) * 1024 + k0 + col;
      const unsigned short* gb = Wd + (size_t)(bn + row) * 1024 + k0 + col;
      __builtin_amdgcn_global_load_lds((const AS1 void*)ga,
                                       (AS3 void*)&As[(i * 256 + w * 64) * 8], 16, 0, 0);
      __builtin_amdgcn_global_load_lds((const AS1 void*)gb,
                                       (AS3 void*)&Bs[(i * 256 + w * 64) * 8], 16, 0, 0);
    }
    __syncthreads();
    short8 av[4], bv[4];
#pragma unroll
    for (int i = 0; i < 4; ++i)
      av[i] = *(const short8*)&As[(wm + i * 16 + rr) * 32 + q * 8];
#pragma unroll
    for (int j = 0; j < 4; ++j)
      bv[j] = *(const short8*)&Bs[(wn + j * 16 + rr) * 32 + q * 8];
#pragma unroll
    for (int i = 0; i < 4; ++i)
#pragma unroll
      for (int j = 0; j < 4; ++j)
        acc[i][j] = __builtin_amdgcn_mfma_f32_16x16x32_bf16(av[i], bv[j], acc[i][j], 0, 0, 0);
    __syncthreads();
  }
#pragma unroll
  for (int i = 0; i < 4; ++i)
#pragma unroll
    for (int j = 0; j < 4; ++j)
#pragma unroll
      for (int reg = 0; reg < 4; ++reg) {
        int row = wm + i * 16 + q * 4 + reg;
        int col = wn + j * 16 + rr;
        float vv = acc[i][j][reg] + bias[bn + col];
        Pd[(size_t)(bm + row) * 4096 + bn + col] = f2bf(vv);
      }
}

// ---------------- persistent recurrence R11: loader/compute wave split ----------
// 256 blocks x 256 thr. dir=bid&1, mc=bid>>1. One __syncthreads per step.
// Waves 0,3 = loaders: poll hg[(t-1)&1] with batched tagged dwordx4 (per-lane
//   adaptive re-poll), extract bf16, stage into double-buffered h_lds; then at
//   the barrier hand off and immediately poll the NEXT step while MFMA runs.
// Waves 1,2 = compute: gate-regrouped MFMA (W_hh frags in 128 VGPRs) -> barrier-
//   free intra-wave LDS transpose -> full LSTM cell epilogue (lanes 0..31) ->
//   tagged publish + h_seq store + P prefetch for t+1. No B3, no epi waves.
// Publish: hg[buf][dir][mc*64 + b*8 + er] = u32(bf16(h)<<16 | (t+1)).
// Ping-pong safety: block X overwrites hg[t&1] only after its loader verified
// ALL tags==t, which transitively requires every block's read of hg[t&1]'s old
// contents (step t-1) to be complete. hg zeroed per launch (tag aliasing).
__global__ __launch_bounds__(256, 1) void k_rec(const unsigned short* __restrict__ WF,
                                                const unsigned short* __restrict__ P,
                                                const int* __restrict__ lengths,
                                                uint* __restrict__ hg,     // [2buf][2dir][8192] u32
                                                float* __restrict__ h_seq) {
  __shared__ __align__(16) unsigned short h_lds[2][8256];  // [buf][b*1032 + k]
  __shared__ float gl[2][128];                             // per-wave transpose pad

  const int bid = blockIdx.x;
  const int dir = bid & 1;
  const int mc  = bid >> 1;
  const int tid = threadIdx.x;
  const int w   = tid >> 6, lane = tid & 63;
  const int q   = lane >> 4;
  const bool mfma_w = (w == 1) || (w == 2);
  const int nt = w - 1;                      // valid for mfma waves

  // ---- compute waves: hoist W_hh B-fragments (loop-invariant, 128 VGPRs) ----
  short8 wfrag[32];
  if (mfma_w) {
    const unsigned short* wbase =
        WF + (((size_t)(dir * 128 + mc) * 2 + nt) * 16384) + lane * 8;
#pragma unroll
    for (int kt = 0; kt < 32; ++kt)
      wfrag[kt] = *(const short8*)&wbase[kt * 512];
  }

  // ---- cell identity (compute waves, lanes 0..31): cb = lane>>2, ceri = lane&3 ----
  const int cb   = (lane & 31) >> 2;
  const int ceri = lane & 3;
  const int cer  = nt * 4 + ceri;
  const bool cell = mfma_w && (lane < 32);
  const int len_c = cell ? lengths[cb] : 0;
  float c_reg = 0.f, h_reg = 0.f;
  const unsigned short* Pd = P + (size_t)dir * 16777216 + mc * 8 + cer;
  unsigned short pv0 = 0, pv1 = 0, pv2 = 0, pv3 = 0;
  if (cell) {  // prefetch P for t=0
    const unsigned short* prow = Pd + (size_t)cb * 4096;
    pv0 = prow[0]; pv1 = prow[1024]; pv2 = prow[2048]; pv3 = prow[3072];
  }

  // ---- loader identity: li in 0..127; thread stages producer-chunk slices ----
  const int li   = ((w == 0) ? 0 : 64) + lane;
  const int lb   = (li & 15) >> 1;      // batch row staged by this thread
  const int lper = (li & 1) * 4;        // er half (0 or 4)
  const int lp0  = li >> 4;             // pmc low bits
  const uint* base0 = hg + (size_t)(0 * 2 + dir) * 8192 + li * 4;
  const uint* base1 = hg + (size_t)(1 * 2 + dir) * 8192 + li * 4;

#define LDG(dst, ptr) \
  asm volatile("global_load_dwordx4 %0, %1, off sc0 sc1" : "=&v"(dst) : "v"(ptr))
#define LOAD16(tb) \
  LDG(r0, (tb));          LDG(r1, (tb) + 512);   LDG(r2, (tb) + 1024);  \
  LDG(r3, (tb) + 1536);   LDG(r4, (tb) + 2048);  LDG(r5, (tb) + 2560);  \
  LDG(r6, (tb) + 3072);   LDG(r7, (tb) + 3584);  LDG(r8, (tb) + 4096);  \
  LDG(r9, (tb) + 4608);   LDG(r10, (tb) + 5120); LDG(r11, (tb) + 5632); \
  LDG(r12, (tb) + 6144);  LDG(r13, (tb) + 6656); LDG(r14, (tb) + 7168); \
  LDG(r15, (tb) + 7680)
#define WAITV                                             \
  asm volatile("s_waitcnt vmcnt(0)" ::: "memory");        \
  __builtin_amdgcn_sched_barrier(0)
#define CHK(r) ((((r).x ^ need) | ((r).y ^ need) | ((r).z ^ need) | ((r).w ^ need)) & 0xffffu)
#define STG(r, kk) do {                                               \
    uint lo_ = ((r).x >> 16) | ((r).y & 0xffff0000u);                 \
    uint hi_ = ((r).z >> 16) | ((r).w & 0xffff0000u);                 \
    *(ull*)&wb[lb * 1032 + ((kk) * 8 + lp0) * 8 + lper] =             \
        (ull)lo_ | ((ull)hi_ << 32);                                  \
  } while (0)

  for (int t = 0; t < 512; ++t) {
    // ================= loader waves: poll + verify + stage h[t-1] ============
    if (!mfma_w && t > 0) {
      const uint need = (uint)t;                      // tag of h[t-1]
      const uint* tb = ((t - 1) & 1) ? base1 : base0;
      unsigned short* wb = h_lds[(t - 1) & 1];
      uintx4 r0, r1, r2, r3, r4, r5, r6, r7, r8, r9, r10, r11, r12, r13, r14, r15;
      LOAD16(tb);
      WAITV;
      uint st = CHK(r0) | CHK(r1) | CHK(r2) | CHK(r3) | CHK(r4) | CHK(r5) |
                CHK(r6) | CHK(r7) | CHK(r8) | CHK(r9) | CHK(r10) | CHK(r11) |
                CHK(r12) | CHK(r13) | CHK(r14) | CHK(r15);
      while (__ballot(st != 0u) != 0ull) {
        if (st != 0u) { LOAD16(tb); }                 // only stale lanes re-poll
        WAITV;
        st = CHK(r0) | CHK(r1) | CHK(r2) | CHK(r3) | CHK(r4) | CHK(r5) |
             CHK(r6) | CHK(r7) | CHK(r8) | CHK(r9) | CHK(r10) | CHK(r11) |
             CHK(r12) | CHK(r13) | CHK(r14) | CHK(r15);
      }
      STG(r0, 0);  STG(r1, 1);  STG(r2, 2);  STG(r3, 3);
      STG(r4, 4);  STG(r5, 5);  STG(r6, 6);  STG(r7, 7);
      STG(r8, 8);  STG(r9, 9);  STG(r10, 10); STG(r11, 11);
      STG(r12, 12); STG(r13, 13); STG(r14, 14); STG(r15, 15);
    }
    __syncthreads();   // B2: h_lds[(t-1)&1] staged; loaders run ahead after this

    // ================= compute waves: MFMA -> transpose -> cell -> publish ====
    if (mfma_w) {
      if (t > 0) {
        const unsigned short* hrow = &h_lds[(t - 1) & 1][(lane & 7) * 1032 + q * 8];
        f32x4 a0 = (f32x4){0.f, 0.f, 0.f, 0.f}, a1 = a0, a2 = a0, a3 = a0;
#pragma unroll
        for (int kt = 0; kt < 32; kt += 4) {
          short8 v0 = *(const short8*)&hrow[(kt + 0) * 32];
          short8 v1 = *(const short8*)&hrow[(kt + 1) * 32];
          short8 v2 = *(const short8*)&hrow[(kt + 2) * 32];
          short8 v3 = *(const short8*)&hrow[(kt + 3) * 32];
          a0 = __builtin_amdgcn_mfma_f32_16x16x32_bf16(v0, wfrag[kt + 0], a0, 0, 0, 0);
          a1 = __builtin_amdgcn_mfma_f32_16x16x32_bf16(v1, wfrag[kt + 1], a1, 0, 0, 0);
          a2 = __builtin_amdgcn_mfma_f32_16x16x32_bf16(v2, wfrag[kt + 2], a2, 0, 0, 0);
          a3 = __builtin_amdgcn_mfma_f32_16x16x32_bf16(v3, wfrag[kt + 3], a3, 0, 0, 0);
        }
        a0 += a1; a2 += a3; a0 += a2;
        // intra-wave transpose via per-wave LDS pad (no barrier):
        // writer lane L<32: C cols n_local=L&15, rows q*4+reg = batch
        if (lane < 32)
          *(f32x4*)&gl[nt][(lane & 15) * 8 + q * 4] = a0;
        asm volatile("s_waitcnt lgkmcnt(0)" ::: "memory");
        __builtin_amdgcn_sched_barrier(0);
      }
      if (cell) {
        float g0 = 0.f, g1 = 0.f, g2 = 0.f, g3 = 0.f;
        if (t > 0) {
          g0 = gl[nt][(0 * 4 + ceri) * 8 + cb];
          g1 = gl[nt][(1 * 4 + ceri) * 8 + cb];
          g2 = gl[nt][(2 * 4 + ceri) * 8 + cb];
          g3 = gl[nt][(3 * 4 + ceri) * 8 + cb];
        }
        if (t < len_c) {
          float gi = g0 + bfl(pv0);
          float gf = g1 + bfl(pv1);
          float gg = g2 + bfl(pv2);
          float go = g3 + bfl(pv3);
          float si = 1.f / (1.f + __expf(-gi));
          float sf = 1.f / (1.f + __expf(-gf));
          float so = 1.f / (1.f + __expf(-go));
          float tg = tanhf(gg);
          float cn = sf * c_reg + si * tg;
          float hn = so * tanhf(cn);
          c_reg = cn;
          h_reg = hn;
          h_seq[((size_t)(dir * 512 + t) * 8 + cb) * 1024 + mc * 8 + cer] = hn;
        }
        // publish (always, frozen h past len): self-validating tagged word
        uint word = ((uint)f2bf(h_reg) << 16) | (uint)(t + 1);
        uint* dst = hg + (size_t)((t & 1) * 2 + dir) * 8192 + mc * 64 + cb * 8 + cer;
        __hip_atomic_store(dst, word, __ATOMIC_RELAXED, __HIP_MEMORY_SCOPE_AGENT);
        // P prefetch for t+1 (register double-buffer, full-step distance)
        if (t < 511) {
          const unsigned short* prow = Pd + ((size_t)(t + 1) * 8 + cb) * 4096;
          pv0 = prow[0]; pv1 = prow[1024]; pv2 = prow[2048]; pv3 = prow[3072];
        }
      }
    }
  }
#undef LDG
#undef LOAD16
#undef WAITV
#undef CHK
#undef STG
}

// ---------------- emissions: emit[t*8+b][k] = [hf, hb(rev)] @ W_emit^T + b_emit ----------------
__global__ __launch_bounds__(64) void k_emit(const float* __restrict__ h_seq,
    const float* __restrict__ WET, const float* __restrict__ b_emit,
    const int* __restrict__ lengths, float* __restrict__ emit) {
  __shared__ float hl[4][2048];
  const int tid = threadIdx.x;
  const int p0 = blockIdx.x * 4;
  for (int i = 0; i < 32; ++i) {
    int idx = tid + i * 64;          // float4 index 0..2047
    int pl = idx >> 9;
    int r = idx & 511;
    int p = p0 + pl;
    int t = p >> 3, b = p & 7;
    int len = lengths[b];
    float4 v = make_float4(0.f, 0.f, 0.f, 0.f);
    if (t < len) {
      if (r < 256) {
        v = *(const float4*)&h_seq[((size_t)t * 8 + b) * 1024 + r * 4];
      } else {
        int tr = len - 1 - t;
        v = *(const float4*)&h_seq[((size_t)(512 + tr) * 8 + b) * 1024 + (r - 256) * 4];
      }
    }
    *(float4*)&hl[pl][r * 4] = v;
  }
  __syncthreads();
  const int k = tid & 15, pl = tid >> 4;
  const int p = p0 + pl;
  const int t = p >> 3, b = p & 7;
  const int len = lengths[b];
  float acc = 0.f;
  if (t < len) {
    const float* hrow = hl[pl];
#pragma unroll 4
    for (int e4 = 0; e4 < 512; ++e4) {
      float4 h4 = *(const float4*)&hrow[e4 * 4];
      acc += h4.x * WET[(e4 * 4 + 0) * 16 + k]
           + h4.y * WET[(e4 * 4 + 1) * 16 + k]
           + h4.z * WET[(e4 * 4 + 2) * 16 + k]
           + h4.w * WET[(e4 * 4 + 3) * 16 + k];
    }
    acc += b_emit[k];
  }
  emit[(size_t)p * 16 + k] = (t < len) ? acc : 0.f;
}

// ---------------- CRF: gold score + forward algorithm, out[b] = logZ - total ----------------
__global__ __launch_bounds__(128) void k_crf(const float* __restrict__ emit,
    const int* __restrict__ tags, const int* __restrict__ lengths,
    const float* __restrict__ trans, float* __restrict__ out) {
  __shared__ float d_lds[8][17];
  __shared__ float tot[8][17];
  __shared__ float totb[8];
  const int tid = threadIdx.x;
  const int b = tid >> 4, k = tid & 15;
  const int len = lengths[b];

  float part = 0.f;
  for (int t = k; t < 512; t += 16) {
    if (t < len) {
      int tg = tags[b * 512 + t];
      part += emit[((size_t)t * 8 + b) * 16 + tg];
      if (t >= 1) part += trans[tags[b * 512 + t - 1] * 16 + tg];
    }
  }
  tot[b][k] = part;

  float trc[16];
#pragma unroll
  for (int i = 0; i < 16; ++i) trc[i] = trans[i * 16 + k];
  d_lds[b][k] = emit[b * 16 + k];
  __syncthreads();
  if (k == 0) {
    float s = 0.f;
    for (int i = 0; i < 16; ++i) s += tot[b][i];
    totb[b] = s;
  }
  __syncthreads();

  for (int t = 1; t < 512; ++t) {
    float nd = 0.f;
    bool upd = (t < len);
    if (upd) {
      float mx = -3.0e38f;
      float v[16];
#pragma unroll
      for (int i = 0; i < 16; ++i) { v[i] = d_lds[b][i] + trc[i]; mx = fmaxf(mx, v[i]); }
      float s = 0.f;
#pragma unroll
      for (int i = 0; i < 16; ++i) s += __expf(v[i] - mx);
      nd = mx + __logf(s) + emit[((size_t)t * 8 + b) * 16 + k];
    }
    __syncthreads();
    if (upd) d_lds[b][k] = nd;
    __syncthreads();
  }

  if (k == 0) {
    float mx = -3.0e38f;
    for (int i = 0; i < 16; ++i) mx = fmaxf(mx, d_lds[b][i]);
    float s = 0.f;
    for (int i = 0; i < 16; ++i) s += __expf(d_lds[b][i] - mx);
    out[b] = (mx + __logf(s)) - totb[b];
  }
}

extern "C" void kernel_launch(void* const* d_in, const int* in_sizes, int n_in,
                              void* d_out, int out_size, void* d_ws, size_t ws_size,
                              hipStream_t stream) {
  const float* x       = (const float*)d_in[0];
  const int*   tags    = (const int*)d_in[1];
  const int*   lengths = (const int*)d_in[2];
  const float* W_ih_f  = (const float*)d_in[3];
  const float* W_hh_f  = (const float*)d_in[4];
  const float* b_f     = (const float*)d_in[5];
  const float* W_ih_b  = (const float*)d_in[6];
  const float* W_hh_b  = (const float*)d_in[7];
  const float* b_b     = (const float*)d_in[8];
  const float* W_emit  = (const float*)d_in[9];
  const float* b_emit  = (const float*)d_in[10];
  const float* trans   = (const float*)d_in[11];
  float* out = (float*)d_out;
  (void)in_sizes; (void)n_in; (void)out_size; (void)ws_size;

  char* ws = (char*)d_ws;
  unsigned short* A    = (unsigned short*)ws; ws += 16777216;   // 2 x 4096 x 1024 bf16
  unsigned short* Wp   = (unsigned short*)ws; ws += 16777216;   // 2 x 4096 x 1024 bf16
  unsigned short* WF   = (unsigned short*)ws; ws += 16777216;   // MFMA-frag-ordered W_hh
  unsigned short* P    = (unsigned short*)ws; ws += 67108864;   // 2 x 4096 x 4096 bf16
  float* h_seq = (float*)ws; ws += 33554432;                    // 2 x 512 x 8 x 1024 f32
  uint*  hg    = (uint*)ws;  ws += 131072;                      // 2buf x 2dir x 8192 u32 tagged
  float* emit  = (float*)ws; ws += 262144;
  float* WET   = (float*)ws; ws += 131072;

  // hg must be zeroed each launch: stale tags from a previous replay could alias
  // this run's tag sequence and let a consumer accept prior-run h values.
  hipMemsetAsync(hg, 0, 131072, stream);
  k_build_A<<<8192, 256, 0, stream>>>(x, lengths, A);
  k_cast_wih<<<8192, 256, 0, stream>>>(W_ih_f, W_ih_b, Wp);
  k_build_wf<<<4096, 256, 0, stream>>>(W_hh_f, W_hh_b, WF);
  k_build_wet<<<128, 256, 0, stream>>>(W_emit, WET);
  k_proj<<<dim3(32, 32, 2), 256, 0, stream>>>(A, Wp, b_f, b_b, P);

  {
    const unsigned short* wf = WF;
    const unsigned short* pp = P;
    const int* ll = lengths;
    uint* hgp = hg; float* hs = h_seq;
    void* args[] = { &wf, &pp, &ll, &hgp, &hs };
    hipLaunchCooperativeKernel((const void*)k_rec, dim3(256), dim3(256),
                               args, 0, stream);
  }

  k_emit<<<1024, 64, 0, stream>>>(h_seq, WET, b_emit, lengths, emit);
  k_crf<<<1, 128, 0, stream>>>(emit, tags, lengths, trans, out);
}

// Round 6
// 1709.632 us; speedup vs baseline: 1.6284x; 1.6284x over previous
//
#include <hip/hip_runtime.h>
#include <hip/hip_cooperative_groups.h>
#include <stdint.h>

typedef unsigned int uint;
typedef unsigned long long ull;
typedef __attribute__((ext_vector_type(8))) short short8;
typedef __attribute__((ext_vector_type(4))) float f32x4;
typedef __attribute__((ext_vector_type(2))) float f32x2;
typedef __attribute__((ext_vector_type(4))) uint uintx4;

#define AS1 __attribute__((address_space(1)))
#define AS3 __attribute__((address_space(3)))

__device__ __forceinline__ unsigned short f2bf(float f) {
  uint u = __float_as_uint(f);
  u += 0x7fffu + ((u >> 16) & 1u);
  return (unsigned short)(u >> 16);
}
__device__ __forceinline__ float bfl(unsigned short s) {
  return __uint_as_float(((uint)s) << 16);
}

// ---------------- build kernels ----------------

// A[dir][m=t*8+b][e] = bf16(x or x_rev), 2 x 4096 x 1024
__global__ __launch_bounds__(256) void k_build_A(const float* __restrict__ x,
                                                 const int* __restrict__ lengths,
                                                 unsigned short* __restrict__ A) {
  int idx = blockIdx.x * 256 + threadIdx.x;   // float4 units, 2*1Mi total
  int dir = idx >> 20;
  int r = idx & 1048575;
  int m = r >> 8;
  int e4 = r & 255;
  int t = m >> 3, b = m & 7;
  int st = t;
  if (dir) { int len = lengths[b]; st = (t < len) ? (len - 1 - t) : t; }
  float4 v = *(const float4*)&x[((size_t)b * 512 + st) * 1024 + e4 * 4];
  ushort4 o;
  o.x = f2bf(v.x); o.y = f2bf(v.y); o.z = f2bf(v.z); o.w = f2bf(v.w);
  *(ushort4*)&A[(size_t)dir * 4194304 + (size_t)m * 1024 + e4 * 4] = o;
}

// Wp[dir][j][e] = bf16(W_ih)
__global__ __launch_bounds__(256) void k_cast_wih(const float* __restrict__ Wf,
                                                  const float* __restrict__ Wb,
                                                  unsigned short* __restrict__ Wp) {
  int idx = blockIdx.x * 256 + threadIdx.x;
  int dir = idx >> 20;
  int r = idx & 1048575;
  const float* src = dir ? Wb : Wf;
  float4 v = *(const float4*)&src[(size_t)r * 4];
  ushort4 o;
  o.x = f2bf(v.x); o.y = f2bf(v.y); o.z = f2bf(v.z); o.w = f2bf(v.w);
  *(ushort4*)&Wp[(size_t)dir * 4194304 + (size_t)r * 4] = o;
}

// WF (R15 layout): W_hh B-fragments for batch-split groups.
// gtid = lane(6) | kt(5) | nt(1) | w(2) | g(5) | dir(1)    (2^20)
// n_local = lane&15 -> gate = n_local>>2, eri = n_local&3
// j = gate*1024 + g*32 + w*8 + nt*4 + eri ; k = kt*32 + (lane>>4)*8 + v, v<8
__global__ __launch_bounds__(256) void k_build_wf(const float* __restrict__ Wf,
                                                  const float* __restrict__ Wb,
                                                  unsigned short* __restrict__ WF) {
  int gtid = blockIdx.x * 256 + threadIdx.x;   // 2^20
  int lane = gtid & 63;
  int kt   = (gtid >> 6) & 31;
  int nt   = (gtid >> 11) & 1;
  int w    = (gtid >> 12) & 3;
  int g    = (gtid >> 14) & 31;
  int dir  = (gtid >> 19) & 1;
  int gate = (lane & 15) >> 2;
  int eri  = lane & 3;
  int j = gate * 1024 + g * 32 + w * 8 + nt * 4 + eri;
  int k0 = kt * 32 + (lane >> 4) * 8;
  const float* src = dir ? Wb : Wf;
  const float* s = &src[(size_t)j * 1024 + k0];
  float4 v0 = *(const float4*)s;
  float4 v1 = *(const float4*)(s + 4);
  ushort4 oa, ob;
  oa.x = f2bf(v0.x); oa.y = f2bf(v0.y); oa.z = f2bf(v0.z); oa.w = f2bf(v0.w);
  ob.x = f2bf(v1.x); ob.y = f2bf(v1.y); ob.z = f2bf(v1.z); ob.w = f2bf(v1.w);
  *(ushort4*)&WF[(size_t)gtid * 8] = oa;
  *(ushort4*)&WF[(size_t)gtid * 8 + 4] = ob;
}

// WET[e][k] = W_emit[k][e]  (fp32)
__global__ __launch_bounds__(256) void k_build_wet(const float* __restrict__ We,
                                                   float* __restrict__ WET) {
  int idx = blockIdx.x * 256 + threadIdx.x;  // 32768
  int e = idx >> 4, k = idx & 15;
  WET[(size_t)e * 16 + k] = We[(size_t)k * 2048 + e];
}

// ---------------- projection GEMM (bf16 MFMA): P[dir][m][j] = A @ W_ih^T + b ----------------
__global__ __launch_bounds__(256) void k_proj(const unsigned short* __restrict__ A,
                                              const unsigned short* __restrict__ Wp,
                                              const float* __restrict__ bfv,
                                              const float* __restrict__ bbv,
                                              unsigned short* __restrict__ P) {
  const int dir = blockIdx.z;
  const unsigned short* Ad = A + (size_t)dir * 4194304;
  const unsigned short* Wd = Wp + (size_t)dir * 4194304;
  const float* bias = dir ? bbv : bfv;
  unsigned short* Pd = P + (size_t)dir * 16777216;
  const int bm = blockIdx.x * 128;
  const int bn = blockIdx.y * 128;
  __shared__ unsigned short As[128 * 32];
  __shared__ unsigned short Bs[128 * 32];
  const int tid = threadIdx.x;
  const int w = tid >> 6, lane = tid & 63;
  const int wm = (w >> 1) * 64, wn = (w & 1) * 64;
  const int q = lane >> 4, rr = lane & 15;

  f32x4 acc[4][4];
#pragma unroll
  for (int i = 0; i < 4; ++i)
#pragma unroll
    for (int j = 0; j < 4; ++j) acc[i][j] = (f32x4){0.f, 0.f, 0.f, 0.f};

  for (int k0 = 0; k0 < 1024; k0 += 32) {
#pragma unroll
    for (int i = 0; i < 2; ++i) {
      int c = i * 256 + tid;
      int row = c >> 2, col = (c & 3) * 8;
      const unsigned short* ga = Ad + (size_t)(bm + row) * 1024 + k0 + col;
      const unsigned short* gb = Wd + (size_t)(bn + row) * 1024 + k0 + col;
      __builtin_amdgcn_global_load_lds((const AS1 void*)ga,
                                       (AS3 void*)&As[(i * 256 + w * 64) * 8], 16, 0, 0);
      __builtin_amdgcn_global_load_lds((const AS1 void*)gb,
                                       (AS3 void*)&Bs[(i * 256 + w * 64) * 8], 16, 0, 0);
    }
    __syncthreads();
    short8 av[4], bv[4];
#pragma unroll
    for (int i = 0; i < 4; ++i)
      av[i] = *(const short8*)&As[(wm + i * 16 + rr) * 32 + q * 8];
#pragma unroll
    for (int j = 0; j < 4; ++j)
      bv[j] = *(const short8*)&Bs[(wn + j * 16 + rr) * 32 + q * 8];
#pragma unroll
    for (int i = 0; i < 4; ++i)
#pragma unroll
      for (int j = 0; j < 4; ++j)
        acc[i][j] = __builtin_amdgcn_mfma_f32_16x16x32_bf16(av[i], bv[j], acc[i][j], 0, 0, 0);
    __syncthreads();
  }
#pragma unroll
  for (int i = 0; i < 4; ++i)
#pragma unroll
    for (int j = 0; j < 4; ++j)
#pragma unroll
      for (int reg = 0; reg < 4; ++reg) {
        int row = wm + i * 16 + q * 4 + reg;
        int col = wn + j * 16 + rr;
        float vv = acc[i][j][reg] + bias[bn + col];
        Pd[(size_t)(bm + row) * 4096 + bn + col] = f2bf(vv);
      }
}

// ---------------- persistent recurrence R15: batch-split sync groups ----------
// 256 blocks x 256 thr, cooperative, static LDS (~10KB). bid -> dir=bid&1,
// bgrp=(bid>>1)&3 (batch pair 2*bgrp,2*bgrp+1), g=bid>>3 (0..31). Groups =
// (dir,bgrp): 8 groups x 32 blocks; a block syncs ONLY with its 31 peers.
// Block owns 32 hidden units x 2 batches; W_hh slice (256KB) entirely in
// VGPRs (64 x short8 = 256/lane). MFMA m-dim = 2 batches (padded to 16).
// Publish: hg[buf][dir][bgrp][g*64 + w*16 + l] = u32(bf16(h)<<16 | (t+1)),
// l = hw*2+mb (hw = hidden-in-wave 0..7, mb = batch 0..1). Self-validating
// tagged words (R10-proven format, absmax 0).
// Consumer: thread owns 8 words (32B) = 4 hidden x 2 batch of one producer:
// ONE wave-uniform reload-until-clean loop of 2 dwordx4 (detect==transfer,
// no sentinel/bulk split), then unscramble into h_lds[buf][mb][k].
// One __syncthreads per step. All asm loads wave-uniform (R11 miscompile
// excluded). No s_getreg, no early return, agent-scope only.
// Ping-pong safety (2-deep, tag=t+1): a block overwrites hg[t&1] at step t
// only after its verify of tags==t, which orders after every peer's reads of
// hg[t&1]'s old contents (peer publishes h[t-1] only after its step-(t-1)
// reads completed). hg zeroed per launch (replay tag aliasing).
__global__ __launch_bounds__(256, 1) void k_rec(const unsigned short* __restrict__ WF,
                                                const unsigned short* __restrict__ P,
                                                const int* __restrict__ lengths,
                                                uint* __restrict__ hg,   // [2][2][4][2048] u32
                                                float* __restrict__ h_seq) {
  __shared__ __align__(16) unsigned short h_lds[2][2][1032];  // [buf][mb][k]
  __shared__ float gl[4][2][16][2];                           // [w][nt][n_local][mb]

  const int bid  = blockIdx.x;
  const int dir  = bid & 1;
  const int bgrp = (bid >> 1) & 3;
  const int g    = bid >> 3;
  const int tid  = threadIdx.x;
  const int w    = tid >> 6, lane = tid & 63;
  const int q    = lane >> 4;

  // ---- W_hh B-fragments in registers (loop-invariant): 64 x short8 = 256 VGPR ----
  short8 wfrag[64];
  {
    const unsigned short* wbase =
        WF + (size_t)((dir * 32 + g) * 4 + w) * 32768 + lane * 8;
#pragma unroll
    for (int nt = 0; nt < 2; ++nt)
#pragma unroll
      for (int kt = 0; kt < 32; ++kt)
        wfrag[nt * 32 + kt] = *(const short8*)&wbase[(nt * 32 + kt) * 512];
  }

  // ---- cell identity: lanes 0..15 of each wave: hw = lane>>1 (0..7), mb = lane&1 ----
  const bool cl   = (lane < 16);
  const int hw    = (lane & 15) >> 1;
  const int mb    = lane & 1;
  const int nts   = hw >> 2, eri = hw & 3;
  const int hu    = g * 32 + w * 8 + hw;
  const int bglob = bgrp * 2 + mb;
  const int len_c = lengths[bglob];
  float c_reg = 0.f, h_reg = 0.f;
  const unsigned short* Pd =
      P + (size_t)dir * 16777216 + (size_t)bglob * 4096 + hu;

  // ---- consumer identity: thread -> 8 words (32B) of its group's hg buffer ----
  // tid*8 words: cg = tid>>3 (producer), cw2 = (tid&7)>>1, half = tid&1
  const int hu0 = (tid >> 3) * 32 + ((tid & 7) >> 1) * 8 + (tid & 1) * 4;
  const uint grp_off = (uint)(dir * 4 + bgrp) * 2048 + (uint)tid * 8;

  for (int t = 0; t < 512; ++t) {
    // ---- P(t) gate-projection loads (cell lanes; retire under poll vmcnt) ----
    unsigned short pv0 = 0, pv1 = 0, pv2 = 0, pv3 = 0;
    if (cl) {
      const unsigned short* prow = Pd + (size_t)t * 32768;  // (t*8)*4096
      pv0 = prow[0]; pv1 = prow[1024]; pv2 = prow[2048]; pv3 = prow[3072];
    }

    // ---- combined detect+transfer: wave-uniform reload until 8 tags clean ----
    if (t > 0) {
      const uint need = (uint)t;   // tag published with h[t-1]
      const uint* bp = hg + (size_t)((t - 1) & 1) * 16384 + grp_off;
      uintx4 r0, r1;
      for (;;) {
        asm volatile(
            "global_load_dwordx4 %0, %2, off sc0 sc1\n\t"
            "global_load_dwordx4 %1, %2, off offset:16 sc0 sc1\n\t"
            "s_waitcnt vmcnt(0)"
            : "=&v"(r0), "=&v"(r1) : "v"(bp) : "memory");
        __builtin_amdgcn_sched_barrier(0);
        uint bad = (r0.x ^ need) | (r0.y ^ need) | (r0.z ^ need) | (r0.w ^ need) |
                   (r1.x ^ need) | (r1.y ^ need) | (r1.z ^ need) | (r1.w ^ need);
        if (__ballot((bad & 0xffffu) != 0u) == 0ull) break;
      }
      // unscramble: even words -> batch0, odd -> batch1; payload = high 16
      ull u0 = (ull)(r0.x >> 16) | ((ull)(r0.z >> 16) << 16) |
               ((ull)(r1.x >> 16) << 32) | ((ull)(r1.z >> 16) << 48);
      ull u1 = (ull)(r0.y >> 16) | ((ull)(r0.w >> 16) << 16) |
               ((ull)(r1.y >> 16) << 32) | ((ull)(r1.w >> 16) << 48);
      *(ull*)&h_lds[(t - 1) & 1][0][hu0] = u0;
      *(ull*)&h_lds[(t - 1) & 1][1][hu0] = u1;
    }
    __syncthreads();   // B1: h_lds[(t-1)&1] fully staged

    // ---- MFMA: 2 n-tiles, k split even/odd for 4 indep chains; W from regs ----
    if (t > 0) {
      const unsigned short* hrow = &h_lds[(t - 1) & 1][lane & 1][q * 8];
      f32x4 a00 = (f32x4){0.f, 0.f, 0.f, 0.f}, a01 = a00, a10 = a00, a11 = a00;
#pragma unroll
      for (int kt = 0; kt < 32; kt += 2) {
        short8 ae = *(const short8*)&hrow[(kt + 0) * 32];
        short8 ao = *(const short8*)&hrow[(kt + 1) * 32];
        a00 = __builtin_amdgcn_mfma_f32_16x16x32_bf16(ae, wfrag[kt + 0], a00, 0, 0, 0);
        a01 = __builtin_amdgcn_mfma_f32_16x16x32_bf16(ao, wfrag[kt + 1], a01, 0, 0, 0);
        a10 = __builtin_amdgcn_mfma_f32_16x16x32_bf16(ae, wfrag[32 + kt + 0], a10, 0, 0, 0);
        a11 = __builtin_amdgcn_mfma_f32_16x16x32_bf16(ao, wfrag[32 + kt + 1], a11, 0, 0, 0);
      }
      a00 += a01;
      a10 += a11;
      // D rows 0,1 (= batch 0,1) live in q==0 lanes, regs 0,1. Intra-wave
      // transpose via per-wave gl pad (lgkmcnt only, no barrier).
      if (lane < 16) {
        *(f32x2*)&gl[w][0][lane][0] = (f32x2){a00[0], a00[1]};
        *(f32x2*)&gl[w][1][lane][0] = (f32x2){a10[0], a10[1]};
      }
      asm volatile("s_waitcnt lgkmcnt(0)" ::: "memory");
      __builtin_amdgcn_sched_barrier(0);
    }

    // ---- wave-local LSTM cell (lanes 0..15) + tagged publish ----
    if (cl) {
      float g0 = 0.f, g1 = 0.f, g2 = 0.f, g3 = 0.f;
      if (t > 0) {
        g0 = gl[w][nts][0 * 4 + eri][mb];
        g1 = gl[w][nts][1 * 4 + eri][mb];
        g2 = gl[w][nts][2 * 4 + eri][mb];
        g3 = gl[w][nts][3 * 4 + eri][mb];
      }
      if (t < len_c) {
        float gi = g0 + bfl(pv0);
        float gf = g1 + bfl(pv1);
        float gg = g2 + bfl(pv2);
        float go = g3 + bfl(pv3);
        float si = 1.f / (1.f + __expf(-gi));
        float sf = 1.f / (1.f + __expf(-gf));
        float so = 1.f / (1.f + __expf(-go));
        float tg = tanhf(gg);
        float cn = sf * c_reg + si * tg;
        float hn = so * tanhf(cn);
        c_reg = cn;
        h_reg = hn;
        h_seq[((size_t)(dir * 512 + t) * 8 + bglob) * 1024 + hu] = hn;
      }
      uint word = ((uint)f2bf(h_reg) << 16) | (uint)(t + 1);
      uint* dst = hg + (size_t)(t & 1) * 16384 + (size_t)(dir * 4 + bgrp) * 2048 +
                  g * 64 + w * 16 + lane;
      __hip_atomic_store(dst, word, __ATOMIC_RELAXED, __HIP_MEMORY_SCOPE_AGENT);
    }
  }
}

// ---------------- emissions: emit[t*8+b][k] = [hf, hb(rev)] @ W_emit^T + b_emit ----------------
__global__ __launch_bounds__(64) void k_emit(const float* __restrict__ h_seq,
    const float* __restrict__ WET, const float* __restrict__ b_emit,
    const int* __restrict__ lengths, float* __restrict__ emit) {
  __shared__ float hl[4][2048];
  const int tid = threadIdx.x;
  const int p0 = blockIdx.x * 4;
  for (int i = 0; i < 32; ++i) {
    int idx = tid + i * 64;          // float4 index 0..2047
    int pl = idx >> 9;
    int r = idx & 511;
    int p = p0 + pl;
    int t = p >> 3, b = p & 7;
    int len = lengths[b];
    float4 v = make_float4(0.f, 0.f, 0.f, 0.f);
    if (t < len) {
      if (r < 256) {
        v = *(const float4*)&h_seq[((size_t)t * 8 + b) * 1024 + r * 4];
      } else {
        int tr = len - 1 - t;
        v = *(const float4*)&h_seq[((size_t)(512 + tr) * 8 + b) * 1024 + (r - 256) * 4];
      }
    }
    *(float4*)&hl[pl][r * 4] = v;
  }
  __syncthreads();
  const int k = tid & 15, pl = tid >> 4;
  const int p = p0 + pl;
  const int t = p >> 3, b = p & 7;
  const int len = lengths[b];
  float acc = 0.f;
  if (t < len) {
    const float* hrow = hl[pl];
#pragma unroll 4
    for (int e4 = 0; e4 < 512; ++e4) {
      float4 h4 = *(const float4*)&hrow[e4 * 4];
      acc += h4.x * WET[(e4 * 4 + 0) * 16 + k]
           + h4.y * WET[(e4 * 4 + 1) * 16 + k]
           + h4.z * WET[(e4 * 4 + 2) * 16 + k]
           + h4.w * WET[(e4 * 4 + 3) * 16 + k];
    }
    acc += b_emit[k];
  }
  emit[(size_t)p * 16 + k] = (t < len) ? acc : 0.f;
}

// ---------------- CRF: gold score + forward algorithm, out[b] = logZ - total ----------------
__global__ __launch_bounds__(128) void k_crf(const float* __restrict__ emit,
    const int* __restrict__ tags, const int* __restrict__ lengths,
    const float* __restrict__ trans, float* __restrict__ out) {
  __shared__ float d_lds[8][17];
  __shared__ float tot[8][17];
  __shared__ float totb[8];
  const int tid = threadIdx.x;
  const int b = tid >> 4, k = tid & 15;
  const int len = lengths[b];

  float part = 0.f;
  for (int t = k; t < 512; t += 16) {
    if (t < len) {
      int tg = tags[b * 512 + t];
      part += emit[((size_t)t * 8 + b) * 16 + tg];
      if (t >= 1) part += trans[tags[b * 512 + t - 1] * 16 + tg];
    }
  }
  tot[b][k] = part;

  float trc[16];
#pragma unroll
  for (int i = 0; i < 16; ++i) trc[i] = trans[i * 16 + k];
  d_lds[b][k] = emit[b * 16 + k];
  __syncthreads();
  if (k == 0) {
    float s = 0.f;
    for (int i = 0; i < 16; ++i) s += tot[b][i];
    totb[b] = s;
  }
  __syncthreads();

  for (int t = 1; t < 512; ++t) {
    float nd = 0.f;
    bool upd = (t < len);
    if (upd) {
      float mx = -3.0e38f;
      float v[16];
#pragma unroll
      for (int i = 0; i < 16; ++i) { v[i] = d_lds[b][i] + trc[i]; mx = fmaxf(mx, v[i]); }
      float s = 0.f;
#pragma unroll
      for (int i = 0; i < 16; ++i) s += __expf(v[i] - mx);
      nd = mx + __logf(s) + emit[((size_t)t * 8 + b) * 16 + k];
    }
    __syncthreads();
    if (upd) d_lds[b][k] = nd;
    __syncthreads();
  }

  if (k == 0) {
    float mx = -3.0e38f;
    for (int i = 0; i < 16; ++i) mx = fmaxf(mx, d_lds[b][i]);
    float s = 0.f;
    for (int i = 0; i < 16; ++i) s += __expf(d_lds[b][i] - mx);
    out[b] = (mx + __logf(s)) - totb[b];
  }
}

extern "C" void kernel_launch(void* const* d_in, const int* in_sizes, int n_in,
                              void* d_out, int out_size, void* d_ws, size_t ws_size,
                              hipStream_t stream) {
  const float* x       = (const float*)d_in[0];
  const int*   tags    = (const int*)d_in[1];
  const int*   lengths = (const int*)d_in[2];
  const float* W_ih_f  = (const float*)d_in[3];
  const float* W_hh_f  = (const float*)d_in[4];
  const float* b_f     = (const float*)d_in[5];
  const float* W_ih_b  = (const float*)d_in[6];
  const float* W_hh_b  = (const float*)d_in[7];
  const float* b_b     = (const float*)d_in[8];
  const float* W_emit  = (const float*)d_in[9];
  const float* b_emit  = (const float*)d_in[10];
  const float* trans   = (const float*)d_in[11];
  float* out = (float*)d_out;
  (void)in_sizes; (void)n_in; (void)out_size; (void)ws_size;

  char* ws = (char*)d_ws;
  unsigned short* A    = (unsigned short*)ws; ws += 16777216;   // 2 x 4096 x 1024 bf16
  unsigned short* Wp   = (unsigned short*)ws; ws += 16777216;   // 2 x 4096 x 1024 bf16
  unsigned short* WF   = (unsigned short*)ws; ws += 16777216;   // MFMA-frag-ordered W_hh
  unsigned short* P    = (unsigned short*)ws; ws += 67108864;   // 2 x 4096 x 4096 bf16
  float* h_seq = (float*)ws; ws += 33554432;                    // 2 x 512 x 8 x 1024 f32
  uint*  hg    = (uint*)ws;  ws += 131072;                      // 2buf x 8grp x 2048 u32 tagged
  float* emit  = (float*)ws; ws += 262144;
  float* WET   = (float*)ws; ws += 131072;

  // hg must be zeroed each launch: stale tags from a previous replay could
  // alias this run's tag sequence.
  hipMemsetAsync(hg, 0, 131072, stream);
  k_build_A<<<8192, 256, 0, stream>>>(x, lengths, A);
  k_cast_wih<<<8192, 256, 0, stream>>>(W_ih_f, W_ih_b, Wp);
  k_build_wf<<<4096, 256, 0, stream>>>(W_hh_f, W_hh_b, WF);
  k_build_wet<<<128, 256, 0, stream>>>(W_emit, WET);
  k_proj<<<dim3(32, 32, 2), 256, 0, stream>>>(A, Wp, b_f, b_b, P);

  {
    const unsigned short* wf = WF;
    const unsigned short* pp = P;
    const int* ll = lengths;
    uint* hgp = hg; float* hs = h_seq;
    void* args[] = { &wf, &pp, &ll, &hgp, &hs };
    hipLaunchCooperativeKernel((const void*)k_rec, dim3(256), dim3(256),
                               args, 0, stream);
  }

  k_emit<<<1024, 64, 0, stream>>>(h_seq, WET, b_emit, lengths, emit);
  k_crf<<<1, 128, 0, stream>>>(emit, tags, lengths, trans, out);
}